// Round 9
// baseline (171.580 us; speedup 1.0000x reference)
//
#include <hip/hip_runtime.h>
#include <math.h>

// MultiSimilarityLoss B=8192 D=128, R14 (= R13 resubmit; R13 bench was an
// infra failure — same "container failed twice" signature as R6, which
// passed unchanged on resubmit. Fusion re-audited: deadlock-impossible by
// capacity (128 consumers < 1024 slots), release/acquire via threadfence +
// device-scope atomics is the standard one-way pattern).
//  - NG=2 (32 i/wave): live regs ~90 < 128 => __launch_bounds__(256,4),
//    zero spill (R11 needed (256,3) for NG=4). Grid 64x32=2048 = exactly two
//    full rounds at 4 blocks/CU.
//  - Exact block-level fast-path test from sorted labels (range disjointness).
//  - k_pos FUSED as 128 consumer blocks (bid>=2048) gated by per-i-strip
//    counters; saves one launch gap, overlaps diagonal work w/ producer tail.

#define B_N   8192
#define DDIM  128
#define NCLS  128
#define JSTR  32             // j-strips (256 j each)
#define NBX   64             // i-strips (128 i each)
#define NPROD (NBX * JSTR)   // 2048 producer blocks

typedef __attribute__((ext_vector_type(8))) short bf16x8;  // 8 bf16 = 4 VGPRs
typedef __attribute__((ext_vector_type(4))) float f32x4;

static constexpr float ONE_EPS  = 1.0f - 1e-5f;
static constexpr float F_MARGIN = 0.1f;
// exp in log2 domain: exp(a*s+b) = exp2(s*a*log2e + b*log2e)
static constexpr float KP2A = -2.8853900817779268f;   // -2 * log2(e)
static constexpr float KP2B =  1.4426950408889634f;   //  1 * log2(e)
static constexpr float KN2A =  57.707801635558536f;   // 40 * log2(e)
static constexpr float KN2B = -28.853900817779268f;   // -20 * log2(e)

__device__ __forceinline__ float exp2_fast(float x) {
#if __has_builtin(__builtin_amdgcn_exp2f)
    return __builtin_amdgcn_exp2f(x);
#else
    return __expf(x * 0.6931471805599453f);
#endif
}

__device__ __forceinline__ ushort rne_bf16(float f) {
    uint u = __float_as_uint(f);
    return (ushort)((u + 0x7fffu + ((u >> 16) & 1u)) >> 16);
}

// fb tiled layout: [tile=row>>4][ks 0..3][q 0..3][c=row&15][8 elems].
// A wave fragment load (fixed ks; lanes (q,c)) is one contiguous 1KB.
__device__ __forceinline__ int fbt_off(int row, int ks, int q) {
    return (((row >> 4) * 16 + ks * 4 + q) * 16 + (row & 15)) * 8;
}

// ---------------------------------------------------------------- K1: prep
__global__ __launch_bounds__(256)
void k_prep(const float* __restrict__ feats, const int* __restrict__ labels,
            ushort* __restrict__ fb, int* __restrict__ plab,
            int* __restrict__ cstart_g, int* __restrict__ cnt,
            float* __restrict__ out)
{
    __shared__ int cnts[NCLS], pre[NCLS], scn[NCLS], lcur[NCLS];
    __shared__ int sdst[256];
    const int t = threadIdx.x, b = blockIdx.x, r0 = b * 256;

    if (t < NCLS) { cnts[t] = 0; pre[t] = 0; }
    __syncthreads();
    for (int idx = t; idx < B_N / 4; idx += 256) {
        const int4 L = ((const int4*)labels)[idx];
        atomicAdd(&cnts[L.x], 1); atomicAdd(&cnts[L.y], 1);
        atomicAdd(&cnts[L.z], 1); atomicAdd(&cnts[L.w], 1);
        if (idx * 4 < r0) {
            atomicAdd(&pre[L.x], 1); atomicAdd(&pre[L.y], 1);
            atomicAdd(&pre[L.z], 1); atomicAdd(&pre[L.w], 1);
        }
    }
    __syncthreads();
    if (t < NCLS) scn[t] = cnts[t];
    __syncthreads();
    #pragma unroll
    for (int off = 1; off < NCLS; off <<= 1) {     // Hillis-Steele inclusive scan
        int v = 0;
        if (t < NCLS && t >= off) v = scn[t - off];
        __syncthreads();
        if (t < NCLS) scn[t] += v;
        __syncthreads();
    }
    if (t < NCLS) {
        const int cs = scn[t] - cnts[t];           // exclusive start
        lcur[t] = cs + pre[t];
        if (b == 0) cstart_g[t] = cs;
    }
    if (b == 0 && t == 0) { cstart_g[NCLS] = B_N; *out = 0.f; }
    if (t < 2) cnt[b * 2 + t] = 0;                 // 32 blocks x 2 = 64 counters
    __syncthreads();

    const int myl = labels[r0 + t];
    const int dst = atomicAdd(&lcur[myl], 1);      // within-class order irrelevant
    plab[dst] = myl;
    sdst[t] = dst;
    __syncthreads();

    // permute + cast fp32->bf16 into tiled layout
    for (int m = 0; m < 32; ++m) {
        const int rowl = m * 8 + (t >> 5), ch = t & 31;
        float4 v = *(const float4*)(feats + (size_t)(r0 + rowl) * DDIM + ch * 4);
        ushort4 o;
        o.x = rne_bf16(v.x); o.y = rne_bf16(v.y);
        o.z = rne_bf16(v.z); o.w = rne_bf16(v.w);
        const int d = sdst[rowl];
        const int k = ch * 4;
        const int off = (((d >> 4) * 16 + (k >> 5) * 4 + ((k >> 3) & 3)) * 16
                         + (d & 15)) * 8 + (k & 7);
        *(ushort4*)(fb + off) = o;
    }
}

// ---------------------------------------------------------------- K2: fused neg pass + class-diagonal finalize
__global__ __launch_bounds__(256, 4)
void k_main(const ushort* __restrict__ fb, const int* __restrict__ plab,
            const int* __restrict__ cstart_g,
            float* __restrict__ maxn_part, float* __restrict__ nsum_part,
            int* __restrict__ cnt, float* __restrict__ out)
{
    const int bid = blockIdx.x;
    const int t = threadIdx.x, w = t >> 6, lane = t & 63, q = lane >> 4, cl = lane & 15;

    if (bid < NPROD) {
        // ================= producer: (bx,by) tile of the full matrix =========
        const int bx = bid & (NBX - 1), by = bid >> 6;
        const int iw0 = bx * 128 + w * 32;         // 32 i-rows per wave (NG=2)
        const int j0  = by * 256;

        // exact disjointness from sorted labels (wave-uniform scalar loads)
        const int lif  = plab[bx * 128], lil = plab[bx * 128 + 127];
        const int ljf0 = plab[j0],       ljl0 = plab[j0 + 255];
        const bool fast = (lil < ljf0) || (ljl0 < lif);

        bf16x8 ifr[2][4];
        #pragma unroll
        for (int g = 0; g < 2; ++g) {
            const int row = iw0 + g * 16 + cl;
            #pragma unroll
            for (int ks = 0; ks < 4; ++ks)
                ifr[g][ks] = *(const bf16x8*)(fb + fbt_off(row, ks, q));
        }

        float vmax[2] = {-INFINITY, -INFINITY};
        float ns[2]   = {0.f, 0.f};

        bf16x8 jfr[4];
        #pragma unroll
        for (int ks = 0; ks < 4; ++ks)
            jfr[ks] = *(const bf16x8*)(fb + fbt_off(j0 + cl, ks, q));

        if (fast) {
            // ---------- all pairs different-label ----------
            #pragma unroll 1
            for (int jt = 0; jt < 16; ++jt) {
                f32x4 acc[2];
                #pragma unroll
                for (int g = 0; g < 2; ++g) {
                    acc[g] = f32x4{0.f, 0.f, 0.f, 0.f};
                    #pragma unroll
                    for (int ks = 0; ks < 4; ++ks)
                        acc[g] = __builtin_amdgcn_mfma_f32_16x16x32_bf16(jfr[ks], ifr[g][ks], acc[g], 0, 0, 0);
                }
                if (jt < 15) {
                    const int jb = j0 + (jt + 1) * 16;
                    #pragma unroll
                    for (int ks = 0; ks < 4; ++ks)
                        jfr[ks] = *(const bf16x8*)(fb + fbt_off(jb + cl, ks, q));
                }
                #pragma unroll
                for (int g = 0; g < 2; ++g) {
                    vmax[g] = fmaxf(vmax[g], fmaxf(fmaxf(acc[g][0], acc[g][1]),
                                                   fmaxf(acc[g][2], acc[g][3])));
                    const float e0 = exp2_fast(fmaf(acc[g][0], KN2A, KN2B));
                    const float e1 = exp2_fast(fmaf(acc[g][1], KN2A, KN2B));
                    const float e2 = exp2_fast(fmaf(acc[g][2], KN2A, KN2B));
                    const float e3 = exp2_fast(fmaf(acc[g][3], KN2A, KN2B));
                    ns[g] += (e0 + e1) + (e2 + e3);
                }
            }
        } else {
            // ---------- near-diagonal: per-tile classification ----------
            int li[2], glf[2], gll[2];
            #pragma unroll
            for (int g = 0; g < 2; ++g) {
                li[g]  = plab[iw0 + g * 16 + cl];
                glf[g] = plab[iw0 + g * 16];
                gll[g] = plab[iw0 + g * 16 + 15];
            }
            int ljf = plab[j0], ljl = plab[j0 + 15];

            #pragma unroll 1
            for (int jt = 0; jt < 16; ++jt) {
                const int jb = j0 + jt * 16;
                bool pn[2], pp[2];
                bool anyMixed = false;
                #pragma unroll
                for (int g = 0; g < 2; ++g) {
                    pn[g] = (gll[g] < ljf) || (ljl < glf[g]);                       // disjoint
                    pp[g] = (glf[g] == gll[g]) && (ljf == ljl) && (glf[g] == ljf);  // one class
                    anyMixed = anyMixed || (!pn[g] && !pp[g]);
                }
                int4 lj = {0, 0, 0, 0};
                if (anyMixed) lj = *(const int4*)(plab + jb + q * 4);

                f32x4 acc[2];
                #pragma unroll
                for (int g = 0; g < 2; ++g) {
                    acc[g] = f32x4{0.f, 0.f, 0.f, 0.f};
                    if (!pp[g]) {                    // pure-pos tile: no negatives
                        #pragma unroll
                        for (int ks = 0; ks < 4; ++ks)
                            acc[g] = __builtin_amdgcn_mfma_f32_16x16x32_bf16(jfr[ks], ifr[g][ks], acc[g], 0, 0, 0);
                    }
                }
                if (jt < 15) {
                    #pragma unroll
                    for (int ks = 0; ks < 4; ++ks)
                        jfr[ks] = *(const bf16x8*)(fb + fbt_off(jb + 16 + cl, ks, q));
                    ljf = plab[jb + 16]; ljl = plab[jb + 31];
                }
                #pragma unroll
                for (int g = 0; g < 2; ++g) {
                    if (pn[g]) {
                        vmax[g] = fmaxf(vmax[g], fmaxf(fmaxf(acc[g][0], acc[g][1]),
                                                       fmaxf(acc[g][2], acc[g][3])));
                        const float e0 = exp2_fast(fmaf(acc[g][0], KN2A, KN2B));
                        const float e1 = exp2_fast(fmaf(acc[g][1], KN2A, KN2B));
                        const float e2 = exp2_fast(fmaf(acc[g][2], KN2A, KN2B));
                        const float e3 = exp2_fast(fmaf(acc[g][3], KN2A, KN2B));
                        ns[g] += (e0 + e1) + (e2 + e3);
                    } else if (!pp[g]) {             // mixed tile
                        #pragma unroll
                        for (int r = 0; r < 4; ++r) {
                            const float sv = acc[g][r];
                            const int ljr = (r == 0) ? lj.x : (r == 1) ? lj.y : (r == 2) ? lj.z : lj.w;
                            const bool same = (li[g] == ljr);
                            vmax[g] = fmaxf(vmax[g], same ? -INFINITY : sv);
                            const float ev = exp2_fast(fmaf(sv, KN2A, KN2B));
                            ns[g] += same ? 0.f : ev;
                        }
                    }
                }
            }
        }

        #pragma unroll
        for (int g = 0; g < 2; ++g) {
            vmax[g] = fmaxf(vmax[g], __shfl_xor(vmax[g], 16, 64));
            vmax[g] = fmaxf(vmax[g], __shfl_xor(vmax[g], 32, 64));
            ns[g]  += __shfl_xor(ns[g], 16, 64);
            ns[g]  += __shfl_xor(ns[g], 32, 64);
        }
        if (q == 0) {
            #pragma unroll
            for (int g = 0; g < 2; ++g) {
                const int row = iw0 + g * 16 + cl;
                maxn_part[by * B_N + row] = vmax[g];
                nsum_part[by * B_N + row] = ns[g];
            }
        }
        __syncthreads();                              // all waves' stores drained
        if (t == 0) { __threadfence(); atomicAdd(&cnt[bx], 1); }   // release
    } else {
        // ================= consumer: class c fold + diagonal + loss ==========
        __shared__ float spb[256], sns[256];
        __shared__ float bsum;
        const int c = bid - NPROD;
        const int s = cstart_g[c], e = cstart_g[c + 1], n = e - s;
        if (t == 0) bsum = 0.f;
        if (n > 0) {
            if (t == 0) {                             // wait for needed i-strips
                const int bx_lo = s >> 7, bx_hi = (e - 1) >> 7;
                for (int b = bx_lo; b <= bx_hi; ++b)
                    while (atomicAdd(&cnt[b], 0) < JSTR) __builtin_amdgcn_s_sleep(8);
                __threadfence();                      // acquire
            }
            __syncthreads();

            for (int r = t; r < n && r < 256; r += 256) {
                float mx = -INFINITY, nsum = 0.f;
                #pragma unroll 4
                for (int js = 0; js < JSTR; ++js) {
                    mx    = fmaxf(mx, maxn_part[js * B_N + s + r]);
                    nsum += nsum_part[js * B_N + s + r];
                }
                spb[r] = fminf(ONE_EPS, mx + F_MARGIN);   // -inf if no negatives
                sns[r] = nsum;
            }
            __syncthreads();

            const int nt = (n + 15) >> 4;
            for (int it = w; it < nt; it += 4) {
                const int il = it * 16 + cl;
                bf16x8 ifr[4];
                #pragma unroll
                for (int ks = 0; ks < 4; ++ks)
                    ifr[ks] = *(const bf16x8*)(fb + fbt_off(s + it * 16 + cl, ks, q));
                const float pbl = (il < n) ? spb[il] : -INFINITY;
                float ps = 0.f, vmin = INFINITY;
                for (int jt = 0; jt < nt; ++jt) {
                    bf16x8 jfr[4];
                    #pragma unroll
                    for (int ks = 0; ks < 4; ++ks)
                        jfr[ks] = *(const bf16x8*)(fb + fbt_off(s + jt * 16 + cl, ks, q));
                    f32x4 acc = {0.f, 0.f, 0.f, 0.f};
                    #pragma unroll
                    for (int ks = 0; ks < 4; ++ks)
                        acc = __builtin_amdgcn_mfma_f32_16x16x32_bf16(jfr[ks], ifr[ks], acc, 0, 0, 0);
                    #pragma unroll
                    for (int r = 0; r < 4; ++r) {
                        const int jl = jt * 16 + q * 4 + r;
                        const float sv = acc[r];
                        const bool inb = (jl < n);
                        vmin = fminf(vmin, (inb && sv < ONE_EPS) ? sv : INFINITY);
                        const float ev = exp2_fast(fmaf(sv, KP2A, KP2B));
                        ps += (inb && sv < pbl) ? ev : 0.f;
                    }
                }
                ps  += __shfl_xor(ps, 16, 64);
                ps  += __shfl_xor(ps, 32, 64);
                vmin = fminf(vmin, __shfl_xor(vmin, 16, 64));
                vmin = fminf(vmin, __shfl_xor(vmin, 32, 64));
                float rl = 0.f;
                if (q == 0 && il < n) {
                    const float pbv = spb[il], nsv = sns[il];
                    // valid: has_neg (pb>-inf), any(pos_mask) (ps>0),
                    //        any(neg_mask)&has_pos (pb > min_pos; false if min_pos=inf)
                    if (pbv > -INFINITY && ps > 0.f && pbv > vmin)
                        rl = log1pf(ps) * 0.5f + log1pf(nsv) * 0.025f;  // /2, /40
                }
                #pragma unroll
                for (int off = 32; off > 0; off >>= 1) rl += __shfl_down(rl, off, 64);
                if (lane == 0) atomicAdd(&bsum, rl);
            }
            __syncthreads();
            if (t == 0) atomicAdd(out, bsum * (1.0f / (float)B_N));
        }
    }
}

// ---------------------------------------------------------------- launch
extern "C" void kernel_launch(void* const* d_in, const int* in_sizes, int n_in,
                              void* d_out, int out_size, void* d_ws, size_t ws_size,
                              hipStream_t stream)
{
    const float* feats  = (const float*)d_in[0];
    const int*   labels = (const int*)d_in[1];

    char* p = (char*)d_ws;
    ushort* fb        = (ushort*)p;  p += (size_t)B_N * DDIM * 2;   // 2 MB tiled bf16
    float*  maxn_part = (float*)p;   p += (size_t)JSTR * B_N * 4;   // 1 MB
    float*  nsum_part = (float*)p;   p += (size_t)JSTR * B_N * 4;   // 1 MB
    int*    plab      = (int*)p;     p += (size_t)B_N * 4;          // 32 KB
    int*    cstart    = (int*)p;     p += 132 * 4;
    int*    cnt       = (int*)p;     p += NBX * 4;                  // 64 counters
    float*  out       = (float*)d_out;

    k_prep<<<32, 256, 0, stream>>>(feats, labels, fb, plab, cstart, cnt, out);
    k_main<<<NPROD + NCLS, 256, 0, stream>>>(fb, plab, cstart,
                                             maxn_part, nsum_part, cnt, out);
}

// Round 10
// 130.317 us; speedup vs baseline: 1.3166x; 1.3166x over previous
//
#include <hip/hip_runtime.h>
#include <math.h>

// MultiSimilarityLoss B=8192 D=128, R15.
// R14 post-mortem: fusion-with-spinning-consumers + NG=2 regressed (110us):
// spinner blocks wasted slots, NG=2 halved per-block MFMA ILP, and the merged
// paths degraded producer codegen (VGPR 52). Both reverted.
// R15 = R11's measured-good producer (NG=4, (256,3), grid 32x32, no spill)
// + LAST-ARRIVAL finalizer (zero spinning): after the release fence, each
// producer atomicAdds cnt[bx]; the 32nd arrival (old==31) — already resident —
// folds its strip's 32 partials and runs the class-diagonal pos pass for its
// 256 rows with per-element plab[i]==plab[j] masking over the 16-aligned
// union of class ranges (classes straddling strips handled exactly; each row
// finalized exactly once by its own strip). Non-last blocks exit. k_pos is
// gone -> 2 launches. Fence pattern identical to R14 (proven correct).

#define B_N   8192
#define DDIM  128
#define NCLS  128
#define JSTR  32             // j-strips (grid.y), 256 j each

typedef __attribute__((ext_vector_type(8))) short bf16x8;  // 8 bf16 = 4 VGPRs
typedef __attribute__((ext_vector_type(4))) float f32x4;

static constexpr float ONE_EPS  = 1.0f - 1e-5f;
static constexpr float F_MARGIN = 0.1f;
// exp in log2 domain: exp(a*s+b) = exp2(s*a*log2e + b*log2e)
static constexpr float KP2A = -2.8853900817779268f;   // -2 * log2(e)
static constexpr float KP2B =  1.4426950408889634f;   //  1 * log2(e)
static constexpr float KN2A =  57.707801635558536f;   // 40 * log2(e)
static constexpr float KN2B = -28.853900817779268f;   // -20 * log2(e)

__device__ __forceinline__ float exp2_fast(float x) {
#if __has_builtin(__builtin_amdgcn_exp2f)
    return __builtin_amdgcn_exp2f(x);
#else
    return __expf(x * 0.6931471805599453f);
#endif
}

__device__ __forceinline__ ushort rne_bf16(float f) {
    uint u = __float_as_uint(f);
    return (ushort)((u + 0x7fffu + ((u >> 16) & 1u)) >> 16);
}

// fb tiled layout: [tile=row>>4][ks 0..3][q 0..3][c=row&15][8 elems].
// A wave fragment load (fixed ks; lanes (q,c)) is one contiguous 1KB.
__device__ __forceinline__ int fbt_off(int row, int ks, int q) {
    return (((row >> 4) * 16 + ks * 4 + q) * 16 + (row & 15)) * 8;
}

// ---------------------------------------------------------------- K1: prep
__global__ __launch_bounds__(256)
void k_prep(const float* __restrict__ feats, const int* __restrict__ labels,
            ushort* __restrict__ fb, int* __restrict__ plab,
            int* __restrict__ cstart_g, int* __restrict__ cnt,
            float* __restrict__ out)
{
    __shared__ int cnts[NCLS], pre[NCLS], scn[NCLS], lcur[NCLS];
    __shared__ int sdst[256];
    const int t = threadIdx.x, b = blockIdx.x, r0 = b * 256;

    if (t < NCLS) { cnts[t] = 0; pre[t] = 0; }
    __syncthreads();
    for (int idx = t; idx < B_N / 4; idx += 256) {
        const int4 L = ((const int4*)labels)[idx];
        atomicAdd(&cnts[L.x], 1); atomicAdd(&cnts[L.y], 1);
        atomicAdd(&cnts[L.z], 1); atomicAdd(&cnts[L.w], 1);
        if (idx * 4 < r0) {
            atomicAdd(&pre[L.x], 1); atomicAdd(&pre[L.y], 1);
            atomicAdd(&pre[L.z], 1); atomicAdd(&pre[L.w], 1);
        }
    }
    __syncthreads();
    if (t < NCLS) scn[t] = cnts[t];
    __syncthreads();
    #pragma unroll
    for (int off = 1; off < NCLS; off <<= 1) {     // Hillis-Steele inclusive scan
        int v = 0;
        if (t < NCLS && t >= off) v = scn[t - off];
        __syncthreads();
        if (t < NCLS) scn[t] += v;
        __syncthreads();
    }
    if (t < NCLS) {
        const int cs = scn[t] - cnts[t];           // exclusive start
        lcur[t] = cs + pre[t];
        if (b == 0) cstart_g[t] = cs;
    }
    if (b == 0 && t == 0) { cstart_g[NCLS] = B_N; *out = 0.f; }
    if (t == 0) cnt[b] = 0;                        // 32 strip counters
    __syncthreads();

    const int myl = labels[r0 + t];
    const int dst = atomicAdd(&lcur[myl], 1);      // within-class order irrelevant
    plab[dst] = myl;
    sdst[t] = dst;
    __syncthreads();

    // permute + cast fp32->bf16 into tiled layout
    for (int m = 0; m < 32; ++m) {
        const int rowl = m * 8 + (t >> 5), ch = t & 31;
        float4 v = *(const float4*)(feats + (size_t)(r0 + rowl) * DDIM + ch * 4);
        ushort4 o;
        o.x = rne_bf16(v.x); o.y = rne_bf16(v.y);
        o.z = rne_bf16(v.z); o.w = rne_bf16(v.w);
        const int d = sdst[rowl];
        const int k = ch * 4;
        const int off = (((d >> 4) * 16 + (k >> 5) * 4 + ((k >> 3) & 3)) * 16
                         + (d & 15)) * 8 + (k & 7);
        *(ushort4*)(fb + off) = o;
    }
}

// ---------------------------------------------------------------- K2: neg pass + last-arrival finalize
__global__ __launch_bounds__(256, 3)
void k_main(const ushort* __restrict__ fb, const int* __restrict__ plab,
            const int* __restrict__ cstart_g,
            float* __restrict__ maxn_part, float* __restrict__ nsum_part,
            int* __restrict__ cnt, float* __restrict__ out)
{
    __shared__ float spb[256], sns[256];
    __shared__ float bsum;
    __shared__ int   is_last;
    const int t = threadIdx.x, w = t >> 6, lane = t & 63, q = lane >> 4, cl = lane & 15;
    const int bx = blockIdx.x, by = blockIdx.y;
    const int iw0 = bx * 256 + w * 64;
    const int j0  = by * 256;

    // ======================= producer (identical to R11 k_neg) =============
    bf16x8 ifr[4][4];
    #pragma unroll
    for (int g = 0; g < 4; ++g) {
        const int row = iw0 + g * 16 + cl;
        #pragma unroll
        for (int ks = 0; ks < 4; ++ks)
            ifr[g][ks] = *(const bf16x8*)(fb + fbt_off(row, ks, q));
    }

    float vmax[4], ns[4];
    #pragma unroll
    for (int g = 0; g < 4; ++g) { vmax[g] = -INFINITY; ns[g] = 0.f; }

    bf16x8 jfr[4];
    #pragma unroll
    for (int ks = 0; ks < 4; ++ks)
        jfr[ks] = *(const bf16x8*)(fb + fbt_off(j0 + cl, ks, q));

    if (bx > by + 1 || by > bx + 1) {
        // ---------- fast path: every pair guaranteed different label ----------
        #pragma unroll 1
        for (int jt = 0; jt < 16; ++jt) {
            f32x4 acc[4];
            #pragma unroll
            for (int g = 0; g < 4; ++g) {
                acc[g] = f32x4{0.f, 0.f, 0.f, 0.f};
                #pragma unroll
                for (int ks = 0; ks < 4; ++ks)
                    acc[g] = __builtin_amdgcn_mfma_f32_16x16x32_bf16(jfr[ks], ifr[g][ks], acc[g], 0, 0, 0);
            }
            if (jt < 15) {
                const int jb = j0 + (jt + 1) * 16;
                #pragma unroll
                for (int ks = 0; ks < 4; ++ks)
                    jfr[ks] = *(const bf16x8*)(fb + fbt_off(jb + cl, ks, q));
            }
            #pragma unroll
            for (int g = 0; g < 4; ++g) {
                vmax[g] = fmaxf(vmax[g], fmaxf(fmaxf(acc[g][0], acc[g][1]),
                                               fmaxf(acc[g][2], acc[g][3])));
                const float e0 = exp2_fast(fmaf(acc[g][0], KN2A, KN2B));
                const float e1 = exp2_fast(fmaf(acc[g][1], KN2A, KN2B));
                const float e2 = exp2_fast(fmaf(acc[g][2], KN2A, KN2B));
                const float e3 = exp2_fast(fmaf(acc[g][3], KN2A, KN2B));
                ns[g] += (e0 + e1) + (e2 + e3);
            }
        }
    } else {
        // ---------- general path: near-diagonal blocks ----------
        int li[4], glf[4], gll[4];
        #pragma unroll
        for (int g = 0; g < 4; ++g) {
            li[g]  = plab[iw0 + g * 16 + cl];
            glf[g] = plab[iw0 + g * 16];
            gll[g] = plab[iw0 + g * 16 + 15];
        }
        int ljf = plab[j0], ljl = plab[j0 + 15];

        #pragma unroll 1
        for (int jt = 0; jt < 16; ++jt) {
            const int jb = j0 + jt * 16;
            bool pn[4], pp[4];
            bool anyMixed = false;
            #pragma unroll
            for (int g = 0; g < 4; ++g) {
                pn[g] = (gll[g] < ljf) || (ljl < glf[g]);                       // disjoint
                pp[g] = (glf[g] == gll[g]) && (ljf == ljl) && (glf[g] == ljf);  // one class
                anyMixed = anyMixed || (!pn[g] && !pp[g]);
            }
            int4 lj = {0, 0, 0, 0};
            if (anyMixed) lj = *(const int4*)(plab + jb + q * 4);

            f32x4 acc[4];
            #pragma unroll
            for (int g = 0; g < 4; ++g) {
                acc[g] = f32x4{0.f, 0.f, 0.f, 0.f};
                if (!pp[g]) {
                    #pragma unroll
                    for (int ks = 0; ks < 4; ++ks)
                        acc[g] = __builtin_amdgcn_mfma_f32_16x16x32_bf16(jfr[ks], ifr[g][ks], acc[g], 0, 0, 0);
                }
            }
            if (jt < 15) {
                #pragma unroll
                for (int ks = 0; ks < 4; ++ks)
                    jfr[ks] = *(const bf16x8*)(fb + fbt_off(jb + 16 + cl, ks, q));
                ljf = plab[jb + 16]; ljl = plab[jb + 31];
            }
            #pragma unroll
            for (int g = 0; g < 4; ++g) {
                if (pn[g]) {
                    vmax[g] = fmaxf(vmax[g], fmaxf(fmaxf(acc[g][0], acc[g][1]),
                                                   fmaxf(acc[g][2], acc[g][3])));
                    const float e0 = exp2_fast(fmaf(acc[g][0], KN2A, KN2B));
                    const float e1 = exp2_fast(fmaf(acc[g][1], KN2A, KN2B));
                    const float e2 = exp2_fast(fmaf(acc[g][2], KN2A, KN2B));
                    const float e3 = exp2_fast(fmaf(acc[g][3], KN2A, KN2B));
                    ns[g] += (e0 + e1) + (e2 + e3);
                } else if (!pp[g]) {                 // mixed tile
                    #pragma unroll
                    for (int r = 0; r < 4; ++r) {
                        const float sv = acc[g][r];
                        const int ljr = (r == 0) ? lj.x : (r == 1) ? lj.y : (r == 2) ? lj.z : lj.w;
                        const bool same = (li[g] == ljr);
                        vmax[g] = fmaxf(vmax[g], same ? -INFINITY : sv);
                        const float ev = exp2_fast(fmaf(sv, KN2A, KN2B));
                        ns[g] += same ? 0.f : ev;
                    }
                }
            }
        }
    }

    #pragma unroll
    for (int g = 0; g < 4; ++g) {
        vmax[g] = fmaxf(vmax[g], __shfl_xor(vmax[g], 16, 64));
        vmax[g] = fmaxf(vmax[g], __shfl_xor(vmax[g], 32, 64));
        ns[g]  += __shfl_xor(ns[g], 16, 64);
        ns[g]  += __shfl_xor(ns[g], 32, 64);
    }
    if (q == 0) {
        #pragma unroll
        for (int g = 0; g < 4; ++g) {
            const int row = iw0 + g * 16 + cl;
            maxn_part[by * B_N + row] = vmax[g];
            nsum_part[by * B_N + row] = ns[g];
        }
    }

    // ======================= last-arrival finalize ==========================
    __syncthreads();                               // all waves' stores drained
    if (t == 0) {
        __threadfence();                           // release
        is_last = (atomicAdd(&cnt[bx], 1) == JSTR - 1);
    }
    __syncthreads();
    if (!is_last) return;

    __threadfence();                               // acquire (all 32 producers' partials)
    if (t == 0) bsum = 0.f;
    {   // fold: 256 rows of strip bx
        const int row = bx * 256 + t;
        float mx = -INFINITY, nsum = 0.f;
        #pragma unroll 4
        for (int js = 0; js < JSTR; ++js) {
            mx    = fmaxf(mx, maxn_part[js * B_N + row]);
            nsum += nsum_part[js * B_N + row];
        }
        spb[t] = fminf(ONE_EPS, mx + F_MARGIN);    // pos bound
        sns[t] = nsum;
    }
    __syncthreads();

    // class-diagonal pos pass for this strip's 256 rows (16 i-tiles)
    for (int it = w; it < 16; it += 4) {
        const int base = bx * 256 + it * 16;
        const int ri   = base + cl;
        const int ci   = plab[ri];
        bf16x8 ifr2[4];
        #pragma unroll
        for (int ks = 0; ks < 4; ++ks)
            ifr2[ks] = *(const bf16x8*)(fb + fbt_off(ri, ks, q));
        const int cf  = plab[base], cll = plab[base + 15];
        const int jlo = cstart_g[cf] & ~15;                   // 16-aligned union
        const int jhi = (cstart_g[cll + 1] + 15) & ~15;       // of class ranges
        const float pbl = spb[it * 16 + cl];
        float ps = 0.f, vmin = INFINITY;
        for (int jb = jlo; jb < jhi; jb += 16) {
            bf16x8 jfr2[4];
            #pragma unroll
            for (int ks = 0; ks < 4; ++ks)
                jfr2[ks] = *(const bf16x8*)(fb + fbt_off(jb + cl, ks, q));
            const int4 lj = *(const int4*)(plab + jb + q * 4);
            f32x4 acc = {0.f, 0.f, 0.f, 0.f};
            #pragma unroll
            for (int ks = 0; ks < 4; ++ks)
                acc = __builtin_amdgcn_mfma_f32_16x16x32_bf16(jfr2[ks], ifr2[ks], acc, 0, 0, 0);
            #pragma unroll
            for (int r = 0; r < 4; ++r) {
                const float sv = acc[r];
                const int ljr = (r == 0) ? lj.x : (r == 1) ? lj.y : (r == 2) ? lj.z : lj.w;
                const bool same = (ci == ljr);                // masks out-of-class j
                vmin = fminf(vmin, (same && sv < ONE_EPS) ? sv : INFINITY);
                const float ev = exp2_fast(fmaf(sv, KP2A, KP2B));
                ps += (same && sv < pbl) ? ev : 0.f;
            }
        }
        ps  += __shfl_xor(ps, 16, 64);
        ps  += __shfl_xor(ps, 32, 64);
        vmin = fminf(vmin, __shfl_xor(vmin, 16, 64));
        vmin = fminf(vmin, __shfl_xor(vmin, 32, 64));
        float rl = 0.f;
        if (q == 0) {
            const float pbv = spb[it * 16 + cl], nsv = sns[it * 16 + cl];
            // valid: has_neg (pb>-inf), any(pos_mask) (ps>0),
            //        any(neg_mask)&has_pos (pb > min_pos; false if min_pos=inf)
            if (pbv > -INFINITY && ps > 0.f && pbv > vmin)
                rl = log1pf(ps) * 0.5f + log1pf(nsv) * 0.025f;   // /2, /40
        }
        #pragma unroll
        for (int off = 32; off > 0; off >>= 1) rl += __shfl_down(rl, off, 64);
        if (lane == 0) atomicAdd(&bsum, rl);
    }
    __syncthreads();
    if (t == 0) atomicAdd(out, bsum * (1.0f / (float)B_N));
}

// ---------------------------------------------------------------- launch
extern "C" void kernel_launch(void* const* d_in, const int* in_sizes, int n_in,
                              void* d_out, int out_size, void* d_ws, size_t ws_size,
                              hipStream_t stream)
{
    const float* feats  = (const float*)d_in[0];
    const int*   labels = (const int*)d_in[1];

    char* p = (char*)d_ws;
    ushort* fb        = (ushort*)p;  p += (size_t)B_N * DDIM * 2;   // 2 MB tiled bf16
    float*  maxn_part = (float*)p;   p += (size_t)JSTR * B_N * 4;   // 1 MB
    float*  nsum_part = (float*)p;   p += (size_t)JSTR * B_N * 4;   // 1 MB
    int*    plab      = (int*)p;     p += (size_t)B_N * 4;          // 32 KB
    int*    cstart    = (int*)p;     p += 132 * 4;
    int*    cnt       = (int*)p;     p += 32 * 4;                   // 32 strip counters
    float*  out       = (float*)d_out;

    k_prep<<<32, 256, 0, stream>>>(feats, labels, fb, plab, cstart, cnt, out);
    k_main<<<dim3(32, JSTR), 256, 0, stream>>>(fb, plab, cstart,
                                               maxn_part, nsum_part, cnt, out);
}

// Round 11
// 108.595 us; speedup vs baseline: 1.5800x; 1.2000x over previous
//
#include <hip/hip_runtime.h>
#include <math.h>

// MultiSimilarityLoss B=8192 D=128, R16.
// R15 post-mortem: per-block __threadfence (device scope) = L2 writeback per
// block on multi-XCD => evicts L2-resident fb + serializes; 68.7us producer.
// Third strike for in-kernel global sync (R8, R14, R15) — kernel boundaries
// are the cheap sync. R16 = proven R11 3-launch skeleton (100.8us) + ONE
// lever in k_neg: all 4 waves read IDENTICAL j-fragments, so stage each 4KB
// j-tile into LDS once per block via async global_load_lds (wave w loads its
// ks=w 1KB chunk: linear src, wave-uniform LDS base + lane*16 — the tiled fb
// layout makes both sides linear), double-buffered; the per-jt __syncthreads
// drains vmcnt, and the stage for jt+1 is issued before jt's MFMA+exp
// epilogue => L2 latency hidden IN-WAVE (occupancy-independent), 4x less L2
// read traffic. ifr stays in regs; (256,3) kept (spill-proof, R11-verified).

#define B_N   8192
#define DDIM  128
#define NCLS  128
#define JSTR  32             // j-strips (grid.y), 256 j each

typedef __attribute__((ext_vector_type(8))) short bf16x8;  // 8 bf16 = 4 VGPRs
typedef __attribute__((ext_vector_type(4))) float f32x4;

static constexpr float ONE_EPS  = 1.0f - 1e-5f;
static constexpr float F_MARGIN = 0.1f;
// exp in log2 domain: exp(a*s+b) = exp2(s*a*log2e + b*log2e)
static constexpr float KP2A = -2.8853900817779268f;   // -2 * log2(e)
static constexpr float KP2B =  1.4426950408889634f;   //  1 * log2(e)
static constexpr float KN2A =  57.707801635558536f;   // 40 * log2(e)
static constexpr float KN2B = -28.853900817779268f;   // -20 * log2(e)

__device__ __forceinline__ float exp2_fast(float x) {
#if __has_builtin(__builtin_amdgcn_exp2f)
    return __builtin_amdgcn_exp2f(x);
#else
    return __expf(x * 0.6931471805599453f);
#endif
}

__device__ __forceinline__ ushort rne_bf16(float f) {
    uint u = __float_as_uint(f);
    return (ushort)((u + 0x7fffu + ((u >> 16) & 1u)) >> 16);
}

// fb tiled layout: [tile=row>>4][ks 0..3][q 0..3][c=row&15][8 elems].
// ushort offset = tile*2048 + ks*512 + q*128 + c*8; a wave fragment load
// (fixed ks; lanes (q,c)) is one contiguous 1KB.
__device__ __forceinline__ int fbt_off(int row, int ks, int q) {
    return (((row >> 4) * 16 + ks * 4 + q) * 16 + (row & 15)) * 8;
}

// ---------------------------------------------------------------- K1: prep
__global__ __launch_bounds__(256)
void k_prep(const float* __restrict__ feats, const int* __restrict__ labels,
            ushort* __restrict__ fb, int* __restrict__ plab,
            int* __restrict__ cstart_g, float* __restrict__ out)
{
    __shared__ int cnts[NCLS], pre[NCLS], scn[NCLS], lcur[NCLS];
    __shared__ int sdst[256];
    const int t = threadIdx.x, b = blockIdx.x, r0 = b * 256;

    if (t < NCLS) { cnts[t] = 0; pre[t] = 0; }
    __syncthreads();
    for (int idx = t; idx < B_N / 4; idx += 256) {
        const int4 L = ((const int4*)labels)[idx];
        atomicAdd(&cnts[L.x], 1); atomicAdd(&cnts[L.y], 1);
        atomicAdd(&cnts[L.z], 1); atomicAdd(&cnts[L.w], 1);
        if (idx * 4 < r0) {
            atomicAdd(&pre[L.x], 1); atomicAdd(&pre[L.y], 1);
            atomicAdd(&pre[L.z], 1); atomicAdd(&pre[L.w], 1);
        }
    }
    __syncthreads();
    if (t < NCLS) scn[t] = cnts[t];
    __syncthreads();
    #pragma unroll
    for (int off = 1; off < NCLS; off <<= 1) {     // Hillis-Steele inclusive scan
        int v = 0;
        if (t < NCLS && t >= off) v = scn[t - off];
        __syncthreads();
        if (t < NCLS) scn[t] += v;
        __syncthreads();
    }
    if (t < NCLS) {
        const int cs = scn[t] - cnts[t];           // exclusive start
        lcur[t] = cs + pre[t];
        if (b == 0) cstart_g[t] = cs;
    }
    if (b == 0 && t == 0) { cstart_g[NCLS] = B_N; *out = 0.f; }
    __syncthreads();

    const int myl = labels[r0 + t];
    const int dst = atomicAdd(&lcur[myl], 1);      // within-class order irrelevant
    plab[dst] = myl;
    sdst[t] = dst;
    __syncthreads();

    // permute + cast fp32->bf16 into tiled layout
    for (int m = 0; m < 32; ++m) {
        const int rowl = m * 8 + (t >> 5), ch = t & 31;
        float4 v = *(const float4*)(feats + (size_t)(r0 + rowl) * DDIM + ch * 4);
        ushort4 o;
        o.x = rne_bf16(v.x); o.y = rne_bf16(v.y);
        o.z = rne_bf16(v.z); o.w = rne_bf16(v.w);
        const int d = sdst[rowl];
        const int k = ch * 4;
        const int off = (((d >> 4) * 16 + (k >> 5) * 4 + ((k >> 3) & 3)) * 16
                         + (d & 15)) * 8 + (k & 7);
        *(ushort4*)(fb + off) = o;
    }
}

// ---------------------------------------------------------------- K2: neg pass, LDS-staged j-tiles
__global__ __launch_bounds__(256, 3)
void k_neg(const ushort* __restrict__ fb, const int* __restrict__ plab,
           float* __restrict__ maxn_part, float* __restrict__ nsum_part)
{
    __shared__ ushort jlds[2][2048];   // 2 x 4KB j-tile double buffer
    const int t = threadIdx.x, w = t >> 6, lane = t & 63, q = lane >> 4, cl = lane & 15;
    const int bx = blockIdx.x, by = blockIdx.y;
    const int iw0 = bx * 256 + w * 64;
    const int j0  = by * 256;

    // stage tile (j0>>4)+jt chunk ks=w: 1KB, linear both sides
    const ushort* jsrc = fb + (size_t)(j0 >> 4) * 2048 + w * 512 + lane * 8;
    #define STAGE(buf, jt)                                                          \
    {                                                                               \
        const ushort* s_ = jsrc + (jt) * 2048;                                      \
        _Pragma("clang diagnostic push")                                            \
        __builtin_amdgcn_global_load_lds(                                           \
            (const __attribute__((address_space(1))) unsigned int*)s_,              \
            (__attribute__((address_space(3))) unsigned int*)&jlds[buf][w * 512],   \
            16, 0, 0);                                                              \
        _Pragma("clang diagnostic pop")                                             \
    }

    // persistent i-side fragments
    bf16x8 ifr[4][4];
    #pragma unroll
    for (int g = 0; g < 4; ++g) {
        const int row = iw0 + g * 16 + cl;
        #pragma unroll
        for (int ks = 0; ks < 4; ++ks)
            ifr[g][ks] = *(const bf16x8*)(fb + fbt_off(row, ks, q));
    }

    float vmax[4], ns[4];
    #pragma unroll
    for (int g = 0; g < 4; ++g) { vmax[g] = -INFINITY; ns[g] = 0.f; }

    STAGE(0, 0);
    __syncthreads();                               // drains vmcnt -> buf0 ready

    if (bx > by + 1 || by > bx + 1) {
        // ---------- fast path: every pair guaranteed different label ----------
        #pragma unroll 1
        for (int jt = 0; jt < 16; ++jt) {
            const int cur = jt & 1;
            if (jt < 15) STAGE(cur ^ 1, jt + 1);   // async, in flight during compute
            bf16x8 jfr[4];
            #pragma unroll
            for (int ks = 0; ks < 4; ++ks)
                jfr[ks] = *(const bf16x8*)&jlds[cur][ks * 512 + q * 128 + cl * 8];
            f32x4 acc[4];
            #pragma unroll
            for (int g = 0; g < 4; ++g) {
                acc[g] = f32x4{0.f, 0.f, 0.f, 0.f};
                #pragma unroll
                for (int ks = 0; ks < 4; ++ks)
                    acc[g] = __builtin_amdgcn_mfma_f32_16x16x32_bf16(jfr[ks], ifr[g][ks], acc[g], 0, 0, 0);
            }
            #pragma unroll
            for (int g = 0; g < 4; ++g) {
                vmax[g] = fmaxf(vmax[g], fmaxf(fmaxf(acc[g][0], acc[g][1]),
                                               fmaxf(acc[g][2], acc[g][3])));
                const float e0 = exp2_fast(fmaf(acc[g][0], KN2A, KN2B));
                const float e1 = exp2_fast(fmaf(acc[g][1], KN2A, KN2B));
                const float e2 = exp2_fast(fmaf(acc[g][2], KN2A, KN2B));
                const float e3 = exp2_fast(fmaf(acc[g][3], KN2A, KN2B));
                ns[g] += (e0 + e1) + (e2 + e3);
            }
            __syncthreads();                       // drains next stage + sync reuse
        }
    } else {
        // ---------- general path: near-diagonal blocks ----------
        int li[4], glf[4], gll[4];
        #pragma unroll
        for (int g = 0; g < 4; ++g) {
            li[g]  = plab[iw0 + g * 16 + cl];
            glf[g] = plab[iw0 + g * 16];
            gll[g] = plab[iw0 + g * 16 + 15];
        }

        #pragma unroll 1
        for (int jt = 0; jt < 16; ++jt) {
            const int cur = jt & 1;
            if (jt < 15) STAGE(cur ^ 1, jt + 1);
            const int jb = j0 + jt * 16;
            const int ljf = plab[jb], ljl = plab[jb + 15];
            bool pn[4], pp[4];
            bool anyMixed = false;
            #pragma unroll
            for (int g = 0; g < 4; ++g) {
                pn[g] = (gll[g] < ljf) || (ljl < glf[g]);                       // disjoint
                pp[g] = (glf[g] == gll[g]) && (ljf == ljl) && (glf[g] == ljf);  // one class
                anyMixed = anyMixed || (!pn[g] && !pp[g]);
            }
            int4 lj = {0, 0, 0, 0};
            if (anyMixed) lj = *(const int4*)(plab + jb + q * 4);

            bf16x8 jfr[4];
            #pragma unroll
            for (int ks = 0; ks < 4; ++ks)
                jfr[ks] = *(const bf16x8*)&jlds[cur][ks * 512 + q * 128 + cl * 8];
            f32x4 acc[4];
            #pragma unroll
            for (int g = 0; g < 4; ++g) {
                acc[g] = f32x4{0.f, 0.f, 0.f, 0.f};
                if (!pp[g]) {                        // pure-pos tile: no negatives
                    #pragma unroll
                    for (int ks = 0; ks < 4; ++ks)
                        acc[g] = __builtin_amdgcn_mfma_f32_16x16x32_bf16(jfr[ks], ifr[g][ks], acc[g], 0, 0, 0);
                }
            }
            #pragma unroll
            for (int g = 0; g < 4; ++g) {
                if (pn[g]) {
                    vmax[g] = fmaxf(vmax[g], fmaxf(fmaxf(acc[g][0], acc[g][1]),
                                                   fmaxf(acc[g][2], acc[g][3])));
                    const float e0 = exp2_fast(fmaf(acc[g][0], KN2A, KN2B));
                    const float e1 = exp2_fast(fmaf(acc[g][1], KN2A, KN2B));
                    const float e2 = exp2_fast(fmaf(acc[g][2], KN2A, KN2B));
                    const float e3 = exp2_fast(fmaf(acc[g][3], KN2A, KN2B));
                    ns[g] += (e0 + e1) + (e2 + e3);
                } else if (!pp[g]) {                 // mixed tile
                    #pragma unroll
                    for (int r = 0; r < 4; ++r) {
                        const float sv = acc[g][r];
                        const int ljr = (r == 0) ? lj.x : (r == 1) ? lj.y : (r == 2) ? lj.z : lj.w;
                        const bool same = (li[g] == ljr);
                        vmax[g] = fmaxf(vmax[g], same ? -INFINITY : sv);
                        const float ev = exp2_fast(fmaf(sv, KN2A, KN2B));
                        ns[g] += same ? 0.f : ev;
                    }
                }
            }
            __syncthreads();
        }
    }

    #pragma unroll
    for (int g = 0; g < 4; ++g) {
        vmax[g] = fmaxf(vmax[g], __shfl_xor(vmax[g], 16, 64));
        vmax[g] = fmaxf(vmax[g], __shfl_xor(vmax[g], 32, 64));
        ns[g]  += __shfl_xor(ns[g], 16, 64);
        ns[g]  += __shfl_xor(ns[g], 32, 64);
    }
    if (q == 0) {
        #pragma unroll
        for (int g = 0; g < 4; ++g) {
            const int row = iw0 + g * 16 + cl;
            maxn_part[by * B_N + row] = vmax[g];
            nsum_part[by * B_N + row] = ns[g];
        }
    }
    #undef STAGE
}

// ---------------------------------------------------------------- K3: fold + diagonal (min_pos, pos sum) + loss
__global__ __launch_bounds__(256)
void k_pos(const ushort* __restrict__ fb, const int* __restrict__ cstart_g,
           const float* __restrict__ maxn_part, const float* __restrict__ nsum_part,
           float* __restrict__ out)
{
    __shared__ float spb[256], sns[256];
    __shared__ float bsum;
    const int c = blockIdx.x, t = threadIdx.x;
    const int w = t >> 6, lane = t & 63, q = lane >> 4, cl = lane & 15;
    const int s = cstart_g[c], e = cstart_g[c + 1], n = e - s;
    if (t == 0) bsum = 0.f;

    // fold j-strip partials for this class's rows
    for (int r = t; r < n && r < 256; r += 256) {
        float mx = -INFINITY, nsum = 0.f;
        #pragma unroll 4
        for (int js = 0; js < JSTR; ++js) {
            mx    = fmaxf(mx, maxn_part[js * B_N + s + r]);
            nsum += nsum_part[js * B_N + s + r];
        }
        spb[r] = fminf(ONE_EPS, mx + F_MARGIN);   // -inf if no negatives
        sns[r] = nsum;
    }
    __syncthreads();

    if (n > 0) {
        const int nt = (n + 15) >> 4;
        for (int it = w; it < nt; it += 4) {
            const int il = it * 16 + cl;
            bf16x8 ifr[4];
            #pragma unroll
            for (int ks = 0; ks < 4; ++ks)
                ifr[ks] = *(const bf16x8*)(fb + fbt_off(s + it * 16 + cl, ks, q));
            const float pbl = (il < n) ? spb[il] : -INFINITY;
            float ps = 0.f, vmin = INFINITY;
            for (int jt = 0; jt < nt; ++jt) {
                bf16x8 jfr[4];
                #pragma unroll
                for (int ks = 0; ks < 4; ++ks)
                    jfr[ks] = *(const bf16x8*)(fb + fbt_off(s + jt * 16 + cl, ks, q));
                f32x4 acc = {0.f, 0.f, 0.f, 0.f};
                #pragma unroll
                for (int ks = 0; ks < 4; ++ks)
                    acc = __builtin_amdgcn_mfma_f32_16x16x32_bf16(jfr[ks], ifr[ks], acc, 0, 0, 0);
                #pragma unroll
                for (int r = 0; r < 4; ++r) {
                    const int jl = jt * 16 + q * 4 + r;
                    const float sv = acc[r];
                    const bool inb = (jl < n);
                    vmin = fminf(vmin, (inb && sv < ONE_EPS) ? sv : INFINITY);
                    const float ev = exp2_fast(fmaf(sv, KP2A, KP2B));
                    ps += (inb && sv < pbl) ? ev : 0.f;
                }
            }
            ps  += __shfl_xor(ps, 16, 64);
            ps  += __shfl_xor(ps, 32, 64);
            vmin = fminf(vmin, __shfl_xor(vmin, 16, 64));
            vmin = fminf(vmin, __shfl_xor(vmin, 32, 64));
            float rl = 0.f;
            if (q == 0 && il < n) {
                const float pbv = spb[il], nsv = sns[il];
                // valid: has_neg (pb>-inf), any(pos_mask) (ps>0),
                //        any(neg_mask)&has_pos (pb > min_pos; false if min_pos=inf)
                if (pbv > -INFINITY && ps > 0.f && pbv > vmin)
                    rl = log1pf(ps) * 0.5f + log1pf(nsv) * 0.025f;  // /2, /40
            }
            #pragma unroll
            for (int off = 32; off > 0; off >>= 1) rl += __shfl_down(rl, off, 64);
            if (lane == 0) atomicAdd(&bsum, rl);
        }
    }
    __syncthreads();
    if (t == 0) atomicAdd(out, bsum * (1.0f / (float)B_N));
}

// ---------------------------------------------------------------- launch
extern "C" void kernel_launch(void* const* d_in, const int* in_sizes, int n_in,
                              void* d_out, int out_size, void* d_ws, size_t ws_size,
                              hipStream_t stream)
{
    const float* feats  = (const float*)d_in[0];
    const int*   labels = (const int*)d_in[1];

    char* p = (char*)d_ws;
    ushort* fb        = (ushort*)p;  p += (size_t)B_N * DDIM * 2;   // 2 MB tiled bf16
    float*  maxn_part = (float*)p;   p += (size_t)JSTR * B_N * 4;   // 1 MB
    float*  nsum_part = (float*)p;   p += (size_t)JSTR * B_N * 4;   // 1 MB
    int*    plab      = (int*)p;     p += (size_t)B_N * 4;          // 32 KB
    int*    cstart    = (int*)p;     p += 132 * 4;
    float*  out       = (float*)d_out;

    k_prep<<<32, 256, 0, stream>>>(feats, labels, fb, plab, cstart, out);
    k_neg<<<dim3(32, JSTR), 256, 0, stream>>>(fb, plab, maxn_part, nsum_part);
    k_pos<<<NCLS, 256, 0, stream>>>(fb, cstart, maxn_part, nsum_part, out);
}

// Round 12
// 106.860 us; speedup vs baseline: 1.6057x; 1.0162x over previous
//
#include <hip/hip_runtime.h>
#include <math.h>

// MultiSimilarityLoss B=8192 D=128, R17: 2 launches via atomic partials +
// last-arrival finalize (NO fences).
// R16 post-mortem: LDS j-staging regressed (barrier lockstep > L2 saving);
// reverted to R11 register-prefetch producer. Ledger: kernels ~52us, total
// ~101us => ~16us/launch tax x3 is HALF the budget. R14/R15 fusion failed on
// per-block device __threadfence; R9 proved the fence-free alternative:
// device atomics ARE coherent. k_main = R11 producer + per-row atomicMax/
// atomicAdd accumulators (131K lane-atomics, R9-proven) + per-i-strip
// last-arrival finalizer (R15's proven strip finalize) reading accumulators
// via atomic-RMW reads (coherent point, no staleness). k_pos eliminated.

#define B_N   8192
#define DDIM  128
#define NCLS  128
#define JSTR  32             // j-strips (grid.y), 256 j each

typedef __attribute__((ext_vector_type(8))) short bf16x8;  // 8 bf16 = 4 VGPRs
typedef __attribute__((ext_vector_type(4))) float f32x4;

static constexpr float ONE_EPS  = 1.0f - 1e-5f;
static constexpr float F_MARGIN = 0.1f;
// exp in log2 domain: exp(a*s+b) = exp2(s*a*log2e + b*log2e)
static constexpr float KP2A = -2.8853900817779268f;   // -2 * log2(e)
static constexpr float KP2B =  1.4426950408889634f;   //  1 * log2(e)
static constexpr float KN2A =  57.707801635558536f;   // 40 * log2(e)
static constexpr float KN2B = -28.853900817779268f;   // -20 * log2(e)

__device__ __forceinline__ float exp2_fast(float x) {
#if __has_builtin(__builtin_amdgcn_exp2f)
    return __builtin_amdgcn_exp2f(x);
#else
    return __expf(x * 0.6931471805599453f);
#endif
}

__device__ __forceinline__ ushort rne_bf16(float f) {
    uint u = __float_as_uint(f);
    return (ushort)((u + 0x7fffu + ((u >> 16) & 1u)) >> 16);
}

// ordered-float <-> uint (monotone): atomicMax on uint == float max.
// enc of any finite/-inf value > 0, so 0 == "never written".
__device__ __forceinline__ unsigned enc_f(float f) {
    unsigned u = __float_as_uint(f);
    return (u & 0x80000000u) ? ~u : (u | 0x80000000u);
}
__device__ __forceinline__ float dec_f(unsigned e) {
    return (e & 0x80000000u) ? __uint_as_float(e ^ 0x80000000u)
                             : __uint_as_float(~e);
}

// fb tiled layout: [tile=row>>4][ks 0..3][q 0..3][c=row&15][8 elems].
// A wave fragment load (fixed ks; lanes (q,c)) is one contiguous 1KB.
__device__ __forceinline__ int fbt_off(int row, int ks, int q) {
    return (((row >> 4) * 16 + ks * 4 + q) * 16 + (row & 15)) * 8;
}

// ---------------------------------------------------------------- K1: prep
__global__ __launch_bounds__(256)
void k_prep(const float* __restrict__ feats, const int* __restrict__ labels,
            ushort* __restrict__ fb, int* __restrict__ plab,
            int* __restrict__ cstart_g, unsigned* __restrict__ maxenc,
            float* __restrict__ nsum, int* __restrict__ cnt,
            float* __restrict__ out)
{
    __shared__ int cnts[NCLS], pre[NCLS], scn[NCLS], lcur[NCLS];
    __shared__ int sdst[256];
    const int t = threadIdx.x, b = blockIdx.x, r0 = b * 256;

    if (t < NCLS) { cnts[t] = 0; pre[t] = 0; }
    __syncthreads();
    for (int idx = t; idx < B_N / 4; idx += 256) {
        const int4 L = ((const int4*)labels)[idx];
        atomicAdd(&cnts[L.x], 1); atomicAdd(&cnts[L.y], 1);
        atomicAdd(&cnts[L.z], 1); atomicAdd(&cnts[L.w], 1);
        if (idx * 4 < r0) {
            atomicAdd(&pre[L.x], 1); atomicAdd(&pre[L.y], 1);
            atomicAdd(&pre[L.z], 1); atomicAdd(&pre[L.w], 1);
        }
    }
    __syncthreads();
    if (t < NCLS) scn[t] = cnts[t];
    __syncthreads();
    #pragma unroll
    for (int off = 1; off < NCLS; off <<= 1) {     // Hillis-Steele inclusive scan
        int v = 0;
        if (t < NCLS && t >= off) v = scn[t - off];
        __syncthreads();
        if (t < NCLS) scn[t] += v;
        __syncthreads();
    }
    if (t < NCLS) {
        const int cs = scn[t] - cnts[t];           // exclusive start
        lcur[t] = cs + pre[t];
        if (b == 0) cstart_g[t] = cs;
    }
    if (b == 0 && t == 0) { cstart_g[NCLS] = B_N; *out = 0.f; }
    // zero-init accumulators (each block its 256-row slice) + strip counters
    maxenc[r0 + t] = 0u;
    nsum[r0 + t]   = 0.f;
    if (t == 0) cnt[b] = 0;                        // 32 strip counters
    __syncthreads();

    const int myl = labels[r0 + t];
    const int dst = atomicAdd(&lcur[myl], 1);      // within-class order irrelevant
    plab[dst] = myl;
    sdst[t] = dst;
    __syncthreads();

    // permute + cast fp32->bf16 into tiled layout
    for (int m = 0; m < 32; ++m) {
        const int rowl = m * 8 + (t >> 5), ch = t & 31;
        float4 v = *(const float4*)(feats + (size_t)(r0 + rowl) * DDIM + ch * 4);
        ushort4 o;
        o.x = rne_bf16(v.x); o.y = rne_bf16(v.y);
        o.z = rne_bf16(v.z); o.w = rne_bf16(v.w);
        const int d = sdst[rowl];
        const int k = ch * 4;
        const int off = (((d >> 4) * 16 + (k >> 5) * 4 + ((k >> 3) & 3)) * 16
                         + (d & 15)) * 8 + (k & 7);
        *(ushort4*)(fb + off) = o;
    }
}

// ---------------------------------------------------------------- K2: neg pass + last-arrival finalize
__global__ __launch_bounds__(256, 3)
void k_main(const ushort* __restrict__ fb, const int* __restrict__ plab,
            const int* __restrict__ cstart_g, unsigned* __restrict__ maxenc,
            float* __restrict__ nsum, int* __restrict__ cnt,
            float* __restrict__ out)
{
    __shared__ float spb[256], sns[256];
    __shared__ float bsum;
    __shared__ int   slast;
    const int t = threadIdx.x, w = t >> 6, lane = t & 63, q = lane >> 4, cl = lane & 15;
    const int bx = blockIdx.x, by = blockIdx.y;
    const int iw0 = bx * 256 + w * 64;
    const int j0  = by * 256;

    // ======================= producer (R11 k_neg, proven) ===================
    bf16x8 ifr[4][4];
    #pragma unroll
    for (int g = 0; g < 4; ++g) {
        const int row = iw0 + g * 16 + cl;
        #pragma unroll
        for (int ks = 0; ks < 4; ++ks)
            ifr[g][ks] = *(const bf16x8*)(fb + fbt_off(row, ks, q));
    }

    float vmax[4], ns[4];
    #pragma unroll
    for (int g = 0; g < 4; ++g) { vmax[g] = -INFINITY; ns[g] = 0.f; }

    bf16x8 jfr[4];
    #pragma unroll
    for (int ks = 0; ks < 4; ++ks)
        jfr[ks] = *(const bf16x8*)(fb + fbt_off(j0 + cl, ks, q));

    if (bx > by + 1 || by > bx + 1) {
        // ---------- fast path: every pair guaranteed different label ----------
        #pragma unroll 1
        for (int jt = 0; jt < 16; ++jt) {
            f32x4 acc[4];
            #pragma unroll
            for (int g = 0; g < 4; ++g) {
                acc[g] = f32x4{0.f, 0.f, 0.f, 0.f};
                #pragma unroll
                for (int ks = 0; ks < 4; ++ks)
                    acc[g] = __builtin_amdgcn_mfma_f32_16x16x32_bf16(jfr[ks], ifr[g][ks], acc[g], 0, 0, 0);
            }
            if (jt < 15) {
                const int jb = j0 + (jt + 1) * 16;
                #pragma unroll
                for (int ks = 0; ks < 4; ++ks)
                    jfr[ks] = *(const bf16x8*)(fb + fbt_off(jb + cl, ks, q));
            }
            #pragma unroll
            for (int g = 0; g < 4; ++g) {
                vmax[g] = fmaxf(vmax[g], fmaxf(fmaxf(acc[g][0], acc[g][1]),
                                               fmaxf(acc[g][2], acc[g][3])));
                const float e0 = exp2_fast(fmaf(acc[g][0], KN2A, KN2B));
                const float e1 = exp2_fast(fmaf(acc[g][1], KN2A, KN2B));
                const float e2 = exp2_fast(fmaf(acc[g][2], KN2A, KN2B));
                const float e3 = exp2_fast(fmaf(acc[g][3], KN2A, KN2B));
                ns[g] += (e0 + e1) + (e2 + e3);
            }
        }
    } else {
        // ---------- general path: near-diagonal blocks ----------
        int li[4], glf[4], gll[4];
        #pragma unroll
        for (int g = 0; g < 4; ++g) {
            li[g]  = plab[iw0 + g * 16 + cl];
            glf[g] = plab[iw0 + g * 16];
            gll[g] = plab[iw0 + g * 16 + 15];
        }
        int ljf = plab[j0], ljl = plab[j0 + 15];

        #pragma unroll 1
        for (int jt = 0; jt < 16; ++jt) {
            const int jb = j0 + jt * 16;
            bool pn[4], pp[4];
            bool anyMixed = false;
            #pragma unroll
            for (int g = 0; g < 4; ++g) {
                pn[g] = (gll[g] < ljf) || (ljl < glf[g]);                       // disjoint
                pp[g] = (glf[g] == gll[g]) && (ljf == ljl) && (glf[g] == ljf);  // one class
                anyMixed = anyMixed || (!pn[g] && !pp[g]);
            }
            int4 lj = {0, 0, 0, 0};
            if (anyMixed) lj = *(const int4*)(plab + jb + q * 4);

            f32x4 acc[4];
            #pragma unroll
            for (int g = 0; g < 4; ++g) {
                acc[g] = f32x4{0.f, 0.f, 0.f, 0.f};
                if (!pp[g]) {
                    #pragma unroll
                    for (int ks = 0; ks < 4; ++ks)
                        acc[g] = __builtin_amdgcn_mfma_f32_16x16x32_bf16(jfr[ks], ifr[g][ks], acc[g], 0, 0, 0);
                }
            }
            if (jt < 15) {
                #pragma unroll
                for (int ks = 0; ks < 4; ++ks)
                    jfr[ks] = *(const bf16x8*)(fb + fbt_off(jb + 16 + cl, ks, q));
                ljf = plab[jb + 16]; ljl = plab[jb + 31];
            }
            #pragma unroll
            for (int g = 0; g < 4; ++g) {
                if (pn[g]) {
                    vmax[g] = fmaxf(vmax[g], fmaxf(fmaxf(acc[g][0], acc[g][1]),
                                                   fmaxf(acc[g][2], acc[g][3])));
                    const float e0 = exp2_fast(fmaf(acc[g][0], KN2A, KN2B));
                    const float e1 = exp2_fast(fmaf(acc[g][1], KN2A, KN2B));
                    const float e2 = exp2_fast(fmaf(acc[g][2], KN2A, KN2B));
                    const float e3 = exp2_fast(fmaf(acc[g][3], KN2A, KN2B));
                    ns[g] += (e0 + e1) + (e2 + e3);
                } else if (!pp[g]) {                 // mixed tile
                    #pragma unroll
                    for (int r = 0; r < 4; ++r) {
                        const float sv = acc[g][r];
                        const int ljr = (r == 0) ? lj.x : (r == 1) ? lj.y : (r == 2) ? lj.z : lj.w;
                        const bool same = (li[g] == ljr);
                        vmax[g] = fmaxf(vmax[g], same ? -INFINITY : sv);
                        const float ev = exp2_fast(fmaf(sv, KN2A, KN2B));
                        ns[g] += same ? 0.f : ev;
                    }
                }
            }
        }
    }

    #pragma unroll
    for (int g = 0; g < 4; ++g) {
        vmax[g] = fmaxf(vmax[g], __shfl_xor(vmax[g], 16, 64));
        vmax[g] = fmaxf(vmax[g], __shfl_xor(vmax[g], 32, 64));
        ns[g]  += __shfl_xor(ns[g], 16, 64);
        ns[g]  += __shfl_xor(ns[g], 32, 64);
    }
    if (q == 0) {
        #pragma unroll
        for (int g = 0; g < 4; ++g) {
            const int row = iw0 + g * 16 + cl;
            // device atomics: coherent by construction, no fence needed.
            // Returning forms (results kept live) => completion unambiguous.
            unsigned om = atomicMax(&maxenc[row], enc_f(vmax[g]));
            float    os = atomicAdd(&nsum[row], ns[g]);
            asm volatile("" :: "v"(om), "v"(os));
        }
    }

    // ======================= last-arrival finalize ==========================
    __syncthreads();                               // drains vmcnt: atomics done
    if (t == 0) slast = (atomicAdd(&cnt[bx], 1) == JSTR - 1);
    __syncthreads();
    if (!slast) return;

    if (t == 0) bsum = 0.f;
    {   // fold via atomic-RMW reads (coherent point; all 32 producers done)
        const int row = bx * 256 + t;
        const unsigned menc = atomicAdd(&maxenc[row], 0u);
        const float    nsv  = atomicAdd(&nsum[row], 0.f);
        const float mxv = (menc != 0u) ? dec_f(menc) : -INFINITY;
        spb[t] = fminf(ONE_EPS, mxv + F_MARGIN);   // -inf if no negatives
        sns[t] = nsv;
    }
    __syncthreads();

    // class-diagonal pos pass for this strip's 256 rows (16 i-tiles)
    for (int it = w; it < 16; it += 4) {
        const int base = bx * 256 + it * 16;
        const int ri   = base + cl;
        const int ci   = plab[ri];
        bf16x8 ifr2[4];
        #pragma unroll
        for (int ks = 0; ks < 4; ++ks)
            ifr2[ks] = *(const bf16x8*)(fb + fbt_off(ri, ks, q));
        const int cf  = plab[base], cll = plab[base + 15];
        const int jlo = cstart_g[cf] & ~15;                   // 16-aligned union
        const int jhi = (cstart_g[cll + 1] + 15) & ~15;       // of class ranges
        const float pbl = spb[it * 16 + cl];
        float ps = 0.f, vmin = INFINITY;
        for (int jb = jlo; jb < jhi; jb += 16) {
            bf16x8 jfr2[4];
            #pragma unroll
            for (int ks = 0; ks < 4; ++ks)
                jfr2[ks] = *(const bf16x8*)(fb + fbt_off(jb + cl, ks, q));
            const int4 lj = *(const int4*)(plab + jb + q * 4);
            f32x4 acc = {0.f, 0.f, 0.f, 0.f};
            #pragma unroll
            for (int ks = 0; ks < 4; ++ks)
                acc = __builtin_amdgcn_mfma_f32_16x16x32_bf16(jfr2[ks], ifr2[ks], acc, 0, 0, 0);
            #pragma unroll
            for (int r = 0; r < 4; ++r) {
                const float sv = acc[r];
                const int ljr = (r == 0) ? lj.x : (r == 1) ? lj.y : (r == 2) ? lj.z : lj.w;
                const bool same = (ci == ljr);                // masks out-of-class j
                vmin = fminf(vmin, (same && sv < ONE_EPS) ? sv : INFINITY);
                const float ev = exp2_fast(fmaf(sv, KP2A, KP2B));
                ps += (same && sv < pbl) ? ev : 0.f;
            }
        }
        ps  += __shfl_xor(ps, 16, 64);
        ps  += __shfl_xor(ps, 32, 64);
        vmin = fminf(vmin, __shfl_xor(vmin, 16, 64));
        vmin = fminf(vmin, __shfl_xor(vmin, 32, 64));
        float rl = 0.f;
        if (q == 0) {
            const float pbv = spb[it * 16 + cl], nsv = sns[it * 16 + cl];
            // valid: has_neg (pb>-inf), any(pos_mask) (ps>0),
            //        any(neg_mask)&has_pos (pb > min_pos; false if min_pos=inf)
            if (pbv > -INFINITY && ps > 0.f && pbv > vmin)
                rl = log1pf(ps) * 0.5f + log1pf(nsv) * 0.025f;   // /2, /40
        }
        #pragma unroll
        for (int off = 32; off > 0; off >>= 1) rl += __shfl_down(rl, off, 64);
        if (lane == 0) atomicAdd(&bsum, rl);
    }
    __syncthreads();
    if (t == 0) atomicAdd(out, bsum * (1.0f / (float)B_N));
}

// ---------------------------------------------------------------- launch
extern "C" void kernel_launch(void* const* d_in, const int* in_sizes, int n_in,
                              void* d_out, int out_size, void* d_ws, size_t ws_size,
                              hipStream_t stream)
{
    const float* feats  = (const float*)d_in[0];
    const int*   labels = (const int*)d_in[1];

    char* p = (char*)d_ws;
    ushort*   fb     = (ushort*)p;   p += (size_t)B_N * DDIM * 2;   // 2 MB tiled bf16
    unsigned* maxenc = (unsigned*)p; p += (size_t)B_N * 4;          // 32 KB
    float*    nsum   = (float*)p;    p += (size_t)B_N * 4;          // 32 KB
    int*      plab   = (int*)p;      p += (size_t)B_N * 4;          // 32 KB
    int*      cstart = (int*)p;      p += 132 * 4;
    int*      cnt    = (int*)p;      p += 32 * 4;                   // strip counters
    float*    out    = (float*)d_out;

    k_prep<<<32, 256, 0, stream>>>(feats, labels, fb, plab, cstart,
                                   maxenc, nsum, cnt, out);
    k_main<<<dim3(32, JSTR), 256, 0, stream>>>(fb, plab, cstart,
                                               maxenc, nsum, cnt, out);
}